// Round 16
// baseline (214.407 us; speedup 1.0000x reference)
//
#include <hip/hip_runtime.h>
#include <math.h>

#define NUM_EMB 8192
#define DIM     64
#define NBATCH  4
#define NVOX    32768
#define TPB     256
#define NSPLIT  4                 // codebook splits (quarter per block)
#define QENT    (NUM_EMB / NSPLIT)
#define CHUNK   64                // entries per buffer (dbuf LDS = 34816B)
#define NCH     (QENT / CHUNK)    // 32 chunks
#define BUFSZ   (CHUNK * 128 * 2 + CHUNK * 16)  // lbh 8K | lbm 8K | cnp4 1K
#define CERT_EPS 0.015f           // v-space gap threshold (err bound ~3.2e-3)
#define RCH     512               // repair: entries per (row,chunk) work item

// output layout (f32, concatenated in return order)
#define OFF_Q     0            // 32768*64
#define OFF_VQ    2097152
#define OFF_COMM  2097153
#define OFF_IDX   2097154      // 32768
#define OFF_PERP  2129922
#define OFF_ENT   2129923
#define OFF_UNIQ  2129924
#define OFF_UTIL  2129925

typedef __bf16 bf16x8 __attribute__((ext_vector_type(8)));
typedef float  f32x4  __attribute__((ext_vector_type(4)));

// async global->LDS, 16B per lane; LDS dest is wave-uniform base + lane*16
#define GLDS16(SRC, DST) __builtin_amdgcn_global_load_lds(                    \
        (const __attribute__((address_space(1))) void*)(SRC),                 \
        (__attribute__((address_space(3))) void*)(DST), 16, 0, 0)

__device__ __forceinline__ unsigned short f2bf(float f) {   // RNE f32->bf16
    unsigned u = __float_as_uint(f);
    unsigned r = u + 0x7FFFu + ((u >> 16) & 1u);
    return (unsigned short)(r >> 16);
}
__device__ __forceinline__ float bf2f(unsigned short h) {
    return __uint_as_float(((unsigned)h) << 16);
}
// monotone float -> sortable uint (non-NaN)
__device__ __forceinline__ unsigned fmap(float f) {
    unsigned u = __float_as_uint(f);
    return (u & 0x80000000u) ? ~u : (u | 0x80000000u);
}

// prep: bf16 2-split of codebook, replicated -||c||^2/2 quads, all scratch
// init, scalar-output zeroing (poisoned 0xAA; stats uses atomicAdd).
__global__ void prep_kernel(const float* __restrict__ cb,
                            unsigned short* __restrict__ cbh,
                            unsigned short* __restrict__ cbm,
                            float* __restrict__ cnp4,
                            unsigned* __restrict__ counts,
                            unsigned* __restrict__ misc,
                            unsigned long long* __restrict__ merge,
                            float* __restrict__ out) {
    int row = blockIdx.x * 4 + (threadIdx.x >> 6);
    int l   = threadIdx.x & 63;
    float f = cb[row * DIM + l];
    unsigned short hh = f2bf(f); float r1 = f - bf2f(hh);
    cbh[row * DIM + l] = hh;
    cbm[row * DIM + l] = f2bf(r1);
    float s = f * f;
#pragma unroll
    for (int o = 32; o > 0; o >>= 1) s += __shfl_xor(s, o, 64);
    if (l < 4) cnp4[row * 4 + l] = -0.5f * s;      // replicated x4 -> b128 C-init

    int gid = blockIdx.x * TPB + threadIdx.x;       // 0..524287
    if (gid < NBATCH * NUM_EMB) counts[gid] = 0;
    if (gid >= 32768 && gid < 65536) merge[gid - 32768] = ~0ull;
    if (gid < 16) misc[gid] = 0;                    // lcount, sqsum, pad
    if (blockIdx.x == 0) {
        if (threadIdx.x < 2) out[OFF_VQ + threadIdx.x] = 0.f;
        if (threadIdx.x < 4) out[OFF_PERP + threadIdx.x] = 0.f;
    }
}

// Single-pass 3-product (hh,hm,mh) MFMA scan — r14 EXACT (empirical optimum:
// 107us, VGPR 64, MfmaUtil 43%; r9-r12/r15 structural deviations all
// regressed; the 2-phase structure's pipe-sum is this kernel's floor).
__global__ __launch_bounds__(TPB) void argmin_kernel(
        const float* __restrict__ z,
        const unsigned short* __restrict__ cbh,
        const unsigned short* __restrict__ cbm,
        const float* __restrict__ cnp4,
        float4* __restrict__ res) {
    __shared__ __align__(16) char lds[2 * BUFSZ];
    // per buffer: [0,8K) lbh | [8K,16K) lbm | [16K,17K) cnp4 quads

    const int t  = threadIdx.x;
    const int l  = t & 63, w = t >> 6;
    const int lc = l & 15, lg = l >> 4;
    const int vb = blockIdx.x >> 2, qh = blockIdx.x & 3;
    const int ebase = qh * QENT;

    union U { bf16x8 v; unsigned short s[8]; };
    U Ah[2][2], Am[2][2];                // on-the-fly 2-split of 32 z rows
#pragma unroll
    for (int set = 0; set < 2; ++set) {
        const float* zp = z + (size_t)(vb * 128 + w * 32 + set * 16 + lc) * DIM + lg * 8;
#pragma unroll
        for (int ks = 0; ks < 2; ++ks)
#pragma unroll
            for (int j = 0; j < 8; ++j) {
                float f = zp[ks * 32 + j];
                unsigned short hh = f2bf(f);
                Ah[set][ks].s[j] = hh;
                Am[set][ks].s[j] = f2bf(f - bf2f(hh));
            }
    }

    float m1[2][4], m2[2][4]; int ix[2][4];
#pragma unroll
    for (int set = 0; set < 2; ++set)
#pragma unroll
        for (int r = 0; r < 4; ++r) {
            m1[set][r] = -INFINITY; m2[set][r] = -INFINITY; ix[set][r] = 0;
        }

    // per-lane LDS read bases: XOR-swizzle folded once; k-step1 = base ^ 64
    const int b0 = (lc * 128 + lg * 16) ^ ((lc & 7) << 4);
    const int b1 = b0 ^ 64;
    const int cb0 = CHUNK * 256 + lc * 16;           // 16K: cnp4 quads

    // stage chunk CH into buffer BUF: linear LDS dest + inverse-swizzled
    // per-lane global source (rule #21; swizzle is an involution).
#define STAGE(CH, BUF) {                                                      \
        const char* sh_ = (const char*)cbh + (size_t)(ebase + (CH) * CHUNK) * 128; \
        const char* sm_ = (const char*)cbm + (size_t)(ebase + (CH) * CHUNK) * 128; \
        _Pragma("unroll")                                                     \
        for (int j = 0; j < 2; ++j) {                                         \
            int lin = (j * 256 + t) * 16;                                     \
            int src = lin ^ (((lin >> 7) & 7) << 4);                          \
            int dstb = lin - l * 16;                                          \
            GLDS16(sh_ + src, (BUF) + dstb);                                  \
            GLDS16(sm_ + src, (BUF) + 8192 + dstb);                           \
        }                                                                     \
        if (t < CHUNK) {                                                      \
            int lin = t * 16;                                                 \
            GLDS16((const char*)cnp4 + (size_t)(ebase + (CH) * CHUNK) * 16 + lin, \
                   (BUF) + 16384 + (lin - l * 16));                           \
        }                                                                     \
    }

    STAGE(0, lds);
    __syncthreads();                                 // vmcnt(0) + barrier

    for (int ch = 0; ch < NCH; ++ch) {
        char* cur = lds + (ch & 1) * BUFSZ;
        if (ch + 1 < NCH) STAGE(ch + 1, lds + ((ch + 1) & 1) * BUFSZ);

        int e0 = ebase + ch * CHUNK + lc;
#pragma unroll
        for (int tile = 0; tile < CHUNK / 16; ++tile) {
            bf16x8 bh0 = *(const bf16x8*)(cur + b0 + tile * 2048);
            bf16x8 bh1 = *(const bf16x8*)(cur + b1 + tile * 2048);
            bf16x8 bm0 = *(const bf16x8*)(cur + 8192 + b0 + tile * 2048);
            bf16x8 bm1 = *(const bf16x8*)(cur + 8192 + b1 + tile * 2048);
            f32x4  c0  = *(const f32x4*)(cur + cb0 + tile * 256);
            int eidx = e0 + tile * 16;
#pragma unroll
            for (int set = 0; set < 2; ++set) {
                f32x4 a = c0;                     // C-init = -||c||^2/2 (free)
                a = __builtin_amdgcn_mfma_f32_16x16x32_bf16(Ah[set][0].v, bh0, a, 0, 0, 0);
                a = __builtin_amdgcn_mfma_f32_16x16x32_bf16(Am[set][0].v, bh0, a, 0, 0, 0);
                a = __builtin_amdgcn_mfma_f32_16x16x32_bf16(Ah[set][0].v, bm0, a, 0, 0, 0);
                a = __builtin_amdgcn_mfma_f32_16x16x32_bf16(Ah[set][1].v, bh1, a, 0, 0, 0);
                a = __builtin_amdgcn_mfma_f32_16x16x32_bf16(Am[set][1].v, bh1, a, 0, 0, 0);
                a = __builtin_amdgcn_mfma_f32_16x16x32_bf16(Ah[set][1].v, bm1, a, 0, 0, 0);
#pragma unroll
                for (int r = 0; r < 4; ++r) {     // D: col=lc, row=lg*4+r (m89)
                    float v = a[r];               // = z.c - ||c||^2/2 exactly
                    m2[set][r] = __builtin_amdgcn_fmed3f(v, m1[set][r], m2[set][r]);
                    if (v > m1[set][r]) { m1[set][r] = v; ix[set][r] = eidx; }
                }
            }
        }
        __syncthreads();   // one barrier/chunk (r14 hazard analysis holds)
    }

    // reduce (max1,idx,max2) across the 16 column-lanes, lowest-idx tiebreak
#pragma unroll
    for (int set = 0; set < 2; ++set)
#pragma unroll
        for (int r = 0; r < 4; ++r) {
            float v1 = m1[set][r], v2 = m2[set][r]; int i1 = ix[set][r];
#pragma unroll
            for (int st = 1; st < 16; st <<= 1) {
                float o1 = __shfl_xor(v1, st, 16);
                float o2 = __shfl_xor(v2, st, 16);
                int   oi = __shfl_xor(i1, st, 16);
                float mn = fminf(v1, o1);
                v2 = fmaxf(fmaxf(v2, o2), mn);
                if (o1 > v1 || (o1 == v1 && oi < i1)) { v1 = o1; i1 = oi; }
            }
            if (lc == 0) {
                int vox = vb * 128 + w * 32 + set * 16 + lg * 4 + r;
                res[(size_t)qh * NVOX + vox] =
                    make_float4(v1, v2, __int_as_float(i1), 0.f);
            }
        }
}

// ---- path B (small ws): combine then gather2, res in d_out ----
__global__ void combine_kernel(const float4* __restrict__ res, float* __restrict__ out) {
    int vox = blockIdx.x * blockDim.x + threadIdx.x;
    float v1 = -INFINITY, v2 = -INFINITY; int idx = 0;
#pragma unroll
    for (int h = 0; h < NSPLIT; ++h) {
        float4 t4 = res[(size_t)h * NVOX + vox];
        float a1 = t4.x, a2 = t4.y; int ai = __float_as_int(t4.z);
        float mn = fminf(v1, a1);
        v2 = fmaxf(fmaxf(v2, a2), mn);
        if (a1 > v1) { v1 = a1; idx = ai; }   // strict >: earlier split wins ties
    }
    unsigned flag = (v1 - v2 < CERT_EPS) ? 0x80000000u : 0u;
    ((unsigned*)out)[OFF_IDX + vox] = (unsigned)idx | flag;
}

// r16 gather: 16 lanes per voxel (grid 2048 blocks, was 128 -> half-idle
// chip + serial 64-float rows per thread). Each lane moves one float4;
// fully coalesced (4 voxels x 1KB per wave).
__global__ void gather2_kernel(const float* __restrict__ z, const int* __restrict__ zc,
        const float* __restrict__ cb, float* __restrict__ out,
        unsigned* __restrict__ counts, float* __restrict__ sqsum,
        unsigned* __restrict__ list, unsigned* __restrict__ lcount) {
    int gid = blockIdx.x * TPB + threadIdx.x;
    int vox = gid >> 4, sub = gid & 15;
    unsigned pk = ((const unsigned*)out)[OFF_IDX + vox];   // 16-lane broadcast (L1)
    float s = 0.f;
    if (pk & 0x80000000u) {
        if (sub == 0) { unsigned pos = atomicAdd(lcount, 1u); list[pos] = vox; }
    } else {
        unsigned idx = pk;
        float4 c4 = ((const float4*)(cb + (size_t)idx * DIM))[sub];
        float4 z4 = ((const float4*)(z + (size_t)vox * DIM))[sub];
        ((float4*)(out + OFF_Q + (size_t)vox * DIM))[sub] = c4;
        float dx = z4.x - c4.x, dy = z4.y - c4.y;
        float dz = z4.z - c4.z, dw = z4.w - c4.w;
        s = dx * dx + dy * dy + dz * dz + dw * dw;
        if (sub == 0) {
            out[OFF_IDX + vox] = (float)idx;
            atomicAdd(&counts[zc[vox * 4] * NUM_EMB + idx], 1u);
        }
    }
#pragma unroll
    for (int o = 32; o > 0; o >>= 1) s += __shfl_down(s, o, 64);
    __shared__ float red[TPB / 64];
    if ((threadIdx.x & 63) == 0) red[threadIdx.x >> 6] = s;
    __syncthreads();
    if (threadIdx.x == 0)
        atomicAdd(sqsum, red[0] + red[1] + red[2] + red[3]);
}

// ---- path A (big ws): fused combine+gather, 16 lanes/voxel, res in ws ----
__global__ void gatherF2_kernel(const float* __restrict__ z, const int* __restrict__ zc,
        const float* __restrict__ cb, const float4* __restrict__ res,
        float* __restrict__ out, unsigned* __restrict__ counts,
        float* __restrict__ sqsum, unsigned* __restrict__ list,
        unsigned* __restrict__ lcount) {
    int gid = blockIdx.x * TPB + threadIdx.x;
    int vox = gid >> 4, sub = gid & 15;
    // lanes sub<NSPLIT load their split's result; butterfly over width 16
    // merges (v1,v2,idx) and broadcasts to all 16 lanes. -inf lanes are
    // neutral (o1 > v1 never fires; o1==v1 only when both -inf, pre-merge).
    float v1 = -INFINITY, v2 = -INFINITY; int idx = 0;
    if (sub < NSPLIT) {
        float4 t4 = res[(size_t)sub * NVOX + vox];
        v1 = t4.x; v2 = t4.y; idx = __float_as_int(t4.z);
    }
#pragma unroll
    for (int st = 1; st < 16; st <<= 1) {
        float o1 = __shfl_xor(v1, st, 16);
        float o2 = __shfl_xor(v2, st, 16);
        int   oi = __shfl_xor(idx, st, 16);
        float mn = fminf(v1, o1);
        v2 = fmaxf(fmaxf(v2, o2), mn);
        if (o1 > v1 || (o1 == v1 && oi < idx)) { v1 = o1; idx = oi; }
    }
    float s = 0.f;
    if (v1 - v2 < CERT_EPS) {
        if (sub == 0) { unsigned pos = atomicAdd(lcount, 1u); list[pos] = vox; }
    } else {
        float4 c4 = ((const float4*)(cb + (size_t)idx * DIM))[sub];
        float4 z4 = ((const float4*)(z + (size_t)vox * DIM))[sub];
        ((float4*)(out + OFF_Q + (size_t)vox * DIM))[sub] = c4;
        float dx = z4.x - c4.x, dy = z4.y - c4.y;
        float dz = z4.z - c4.z, dw = z4.w - c4.w;
        s = dx * dx + dy * dy + dz * dz + dw * dw;
        if (sub == 0) {
            out[OFF_IDX + vox] = (float)idx;
            atomicAdd(&counts[zc[vox * 4] * NUM_EMB + idx], 1u);
        }
    }
#pragma unroll
    for (int o = 32; o > 0; o >>= 1) s += __shfl_down(s, o, 64);
    __shared__ float red[TPB / 64];
    if ((threadIdx.x & 63) == 0) red[threadIdx.x >> 6] = s;
    __syncthreads();
    if (threadIdx.x == 0)
        atomicAdd(sqsum, red[0] + red[1] + red[2] + red[3]);
}

// Repair scan: (flagged row, 512-entry chunk) items over 2048 waves;
// coalesced 4-entry groups, x4 interleaved reduce chains; exact f32 dists
// merged via packed (sortable<<32)|idx u64 atomicMin (lowest-idx ties).
__global__ void repair_scan_kernel(const float* __restrict__ z,
        const float* __restrict__ cb, const unsigned* __restrict__ list,
        const unsigned* __restrict__ lcount,
        unsigned long long* __restrict__ merge) {
    int wid = (blockIdx.x * blockDim.x + threadIdx.x) >> 6;
    int l   = threadIdx.x & 63;
    int nw  = (gridDim.x * blockDim.x) >> 6;
    int nitems = (int)*lcount * (NUM_EMB / RCH);
    int sub = l & 15, ent = l >> 4;

    for (int it = wid; it < nitems; it += nw) {
        int k    = it / (NUM_EMB / RCH);
        int base = (it % (NUM_EMB / RCH)) * RCH;
        int vox  = list[k];
        float4 z4 = ((const float4*)(z + (size_t)vox * DIM))[sub];
        float m = INFINITY; int mi = 0;

        for (int g0 = 0; g0 < RCH / 4; g0 += 4) {
            float d[4];
#pragma unroll
            for (int u = 0; u < 4; ++u) {
                int e = base + (g0 + u) * 4 + ent;
                float4 c4 = ((const float4*)(cb + (size_t)e * DIM))[sub];
                float dx = z4.x - c4.x, dy = z4.y - c4.y;
                float dz = z4.z - c4.z, dw = z4.w - c4.w;
                d[u] = fmaf(dx, dx, fmaf(dy, dy, fmaf(dz, dz, dw * dw)));
            }
#pragma unroll
            for (int st = 1; st < 16; st <<= 1)     // 4 independent chains
#pragma unroll
                for (int u = 0; u < 4; ++u) d[u] += __shfl_xor(d[u], st, 16);
#pragma unroll
            for (int u = 0; u < 4; ++u) {
                int e = base + (g0 + u) * 4 + ent;
                if (d[u] < m) { m = d[u]; mi = e; }  // ascending e: lowest-idx
            }
        }
#pragma unroll
        for (int st = 32; st > 0; st >>= 1) {
            float om = __shfl_xor(m, st, 64);
            int   oi = __shfl_xor(mi, st, 64);
            if (om < m || (om == m && oi < mi)) { m = om; mi = oi; }
        }
        if (l == 0) {
            unsigned long long key =
                ((unsigned long long)fmap(m) << 32) | (unsigned)mi;
            atomicMin(&merge[vox], key);
        }
    }
}

// apply repaired argmin: Q row, idx, counts, sqsum for flagged rows
__global__ void repair_apply_kernel(const float* __restrict__ z,
        const int* __restrict__ zc, const float* __restrict__ cb,
        const unsigned* __restrict__ list, const unsigned* __restrict__ lcount,
        const unsigned long long* __restrict__ merge, float* __restrict__ out,
        unsigned* __restrict__ counts, float* __restrict__ sqsum) {
    int wid = (blockIdx.x * blockDim.x + threadIdx.x) >> 6;
    int l   = threadIdx.x & 63;
    int n   = (int)*lcount;
    int nw  = (gridDim.x * blockDim.x) >> 6;
    for (int k = wid; k < n; k += nw) {
        int vox = list[k];
        int mi  = (int)(merge[vox] & 0xFFFFFFFFull);
        float cv = cb[(size_t)mi * DIM + l];
        float zv = z[(size_t)vox * DIM + l];
        out[OFF_Q + (size_t)vox * DIM + l] = cv;
        float df = zv - cv;
        float s = df * df;
#pragma unroll
        for (int st = 32; st > 0; st >>= 1) s += __shfl_xor(s, st, 64);
        if (l == 0) {
            out[OFF_IDX + vox] = (float)mi;
            atomicAdd(&counts[zc[vox * 4] * NUM_EMB + mi], 1u);
            atomicAdd(sqsum, s);
        }
    }
}

// per-batch entropy/unique + fused finalize via atomicAdd on zeroed scalars
__global__ void stats_final_kernel(const unsigned* __restrict__ counts,
                                   const float* __restrict__ sqsum,
                                   float* __restrict__ out) {
    int b = blockIdx.x;
    const unsigned* c = counts + b * NUM_EMB;

    __shared__ float sred[TPB / 64];
    float nf = 0.f;
    for (int i = threadIdx.x; i < NUM_EMB; i += TPB) nf += (float)c[i];
#pragma unroll
    for (int o = 32; o > 0; o >>= 1) nf += __shfl_down(nf, o, 64);
    if ((threadIdx.x & 63) == 0) sred[threadIdx.x >> 6] = nf;
    __syncthreads();
    float n = sred[0] + sred[1] + sred[2] + sred[3];
    __syncthreads();

    float ent = 0.f, uniq = 0.f;
    for (int i = threadIdx.x; i < NUM_EMB; i += TPB) {
        unsigned ci = c[i];
        if (ci) {
            float p = (float)ci / n;
            ent -= p * logf(p + 1e-10f);
            uniq += 1.f;
        }
    }
#pragma unroll
    for (int o = 32; o > 0; o >>= 1) {
        ent  += __shfl_down(ent, o, 64);
        uniq += __shfl_down(uniq, o, 64);
    }
    __shared__ float e4[TPB / 64], u4[TPB / 64];
    if ((threadIdx.x & 63) == 0) { e4[threadIdx.x >> 6] = ent; u4[threadIdx.x >> 6] = uniq; }
    __syncthreads();
    if (threadIdx.x == 0) {
        float eb = e4[0] + e4[1] + e4[2] + e4[3];
        float ub = u4[0] + u4[1] + u4[2] + u4[3];
        atomicAdd(&out[OFF_ENT],  eb * 0.25f);
        atomicAdd(&out[OFF_PERP], expf(eb) * 0.25f);
        atomicAdd(&out[OFF_UNIQ], ub * 0.25f);
        atomicAdd(&out[OFF_UTIL], ub * (100.f / (4.f * NUM_EMB)));
        if (b == 0) {
            float loss = *sqsum / (float)((size_t)NVOX * DIM);
            out[OFF_VQ]   = loss;
            out[OFF_COMM] = loss;
        }
    }
}

extern "C" void kernel_launch(void* const* d_in, const int* in_sizes, int n_in,
                              void* d_out, int out_size, void* d_ws, size_t ws_size,
                              hipStream_t stream) {
    const float* z  = (const float*)d_in[0];
    const int*   zc = (const int*)d_in[1];
    const float* cb = (const float*)d_in[2];
    float* out = (float*)d_out;
    char* ws = (char*)d_ws;

    // d_out scratch: cbh 1MB | cbm 1MB at Q floats [0, 524288).
    unsigned short* cbh = (unsigned short*)out;
    unsigned short* cbm = cbh + NUM_EMB * DIM;

    unsigned* counts = (unsigned*)ws;                       // 131072 B
    unsigned* list   = (unsigned*)(ws + 131072);            // 131072 B
    unsigned* misc   = (unsigned*)(ws + 262144);            // 64 B
    unsigned* lcount = misc;
    float*    sqsum  = (float*)(ws + 262148);
    float*    cnp4   = (float*)(ws + 262208);               // 131072 B
    unsigned long long* merge = (unsigned long long*)(ws + 393280); // 262144 B
    // path A: res in ws (2MB) -> fused combine+gather
    size_t res_ws_off = 655424;
    bool bigws = ws_size >= res_ws_off + (size_t)NSPLIT * NVOX * 16;
    float4* res = bigws ? (float4*)(ws + res_ws_off)
                        : (float4*)(out + 524288);  // path B: floats [524288,1048576)

    prep_kernel<<<NUM_EMB / 4, TPB, 0, stream>>>(cb, cbh, cbm, cnp4, counts,
                                                 misc, merge, out);
    argmin_kernel<<<(NVOX / 128) * NSPLIT, TPB, 0, stream>>>(z, cbh, cbm, cnp4, res);
    if (bigws) {
        gatherF2_kernel<<<(NVOX * 16) / TPB, TPB, 0, stream>>>(z, zc, cb, res, out,
                                                               counts, sqsum, list, lcount);
    } else {
        combine_kernel<<<NVOX / TPB, TPB, 0, stream>>>(res, out);
        gather2_kernel<<<(NVOX * 16) / TPB, TPB, 0, stream>>>(z, zc, cb, out, counts,
                                                              sqsum, list, lcount);
    }
    repair_scan_kernel<<<512, TPB, 0, stream>>>(z, cb, list, lcount, merge);
    repair_apply_kernel<<<64, TPB, 0, stream>>>(z, zc, cb, list, lcount, merge,
                                                out, counts, sqsum);
    stats_final_kernel<<<NBATCH, TPB, 0, stream>>>(counts, sqsum, out);
}

// Round 17
// 193.784 us; speedup vs baseline: 1.1064x; 1.1064x over previous
//
#include <hip/hip_runtime.h>
#include <math.h>

#define NUM_EMB 8192
#define DIM     64
#define NBATCH  4
#define NVOX    32768
#define TPB     256
#define NSPLIT  4                 // codebook splits (quarter per block)
#define QENT    (NUM_EMB / NSPLIT)
#define CHUNK   64                // entries per buffer (dbuf LDS = 34816B)
#define NCH     (QENT / CHUNK)    // 32 chunks
#define BUFSZ   (CHUNK * 128 * 2 + CHUNK * 16)  // lbh 8K | lbm 8K | cnp4 1K
#define CERT_EPS 0.015f           // v-space gap threshold (err bound ~3.2e-3)
#define RCH     512               // repair: entries per (row,chunk) work item

// output layout (f32, concatenated in return order)
#define OFF_Q     0            // 32768*64
#define OFF_VQ    2097152
#define OFF_COMM  2097153
#define OFF_IDX   2097154      // 32768
#define OFF_PERP  2129922
#define OFF_ENT   2129923
#define OFF_UNIQ  2129924
#define OFF_UTIL  2129925

typedef __bf16 bf16x8 __attribute__((ext_vector_type(8)));
typedef float  f32x4  __attribute__((ext_vector_type(4)));

// async global->LDS, 16B per lane; LDS dest is wave-uniform base + lane*16
#define GLDS16(SRC, DST) __builtin_amdgcn_global_load_lds(                    \
        (const __attribute__((address_space(1))) void*)(SRC),                 \
        (__attribute__((address_space(3))) void*)(DST), 16, 0, 0)

__device__ __forceinline__ unsigned short f2bf(float f) {   // RNE f32->bf16
    unsigned u = __float_as_uint(f);
    unsigned r = u + 0x7FFFu + ((u >> 16) & 1u);
    return (unsigned short)(r >> 16);
}
__device__ __forceinline__ float bf2f(unsigned short h) {
    return __uint_as_float(((unsigned)h) << 16);
}
// monotone float -> sortable uint (non-NaN)
__device__ __forceinline__ unsigned fmap(float f) {
    unsigned u = __float_as_uint(f);
    return (u & 0x80000000u) ? ~u : (u | 0x80000000u);
}

// prep: bf16 2-split of codebook, replicated -||c||^2/2 quads, all scratch
// init, scalar-output zeroing (poisoned 0xAA; stats uses atomicAdd).
__global__ void prep_kernel(const float* __restrict__ cb,
                            unsigned short* __restrict__ cbh,
                            unsigned short* __restrict__ cbm,
                            float* __restrict__ cnp4,
                            unsigned* __restrict__ counts,
                            unsigned* __restrict__ misc,
                            unsigned long long* __restrict__ merge,
                            float* __restrict__ out) {
    int row = blockIdx.x * 4 + (threadIdx.x >> 6);
    int l   = threadIdx.x & 63;
    float f = cb[row * DIM + l];
    unsigned short hh = f2bf(f); float r1 = f - bf2f(hh);
    cbh[row * DIM + l] = hh;
    cbm[row * DIM + l] = f2bf(r1);
    float s = f * f;
#pragma unroll
    for (int o = 32; o > 0; o >>= 1) s += __shfl_xor(s, o, 64);
    if (l < 4) cnp4[row * 4 + l] = -0.5f * s;      // replicated x4 -> b128 C-init

    int gid = blockIdx.x * TPB + threadIdx.x;       // 0..524287
    if (gid < NBATCH * NUM_EMB) counts[gid] = 0;
    if (gid >= 32768 && gid < 65536) merge[gid - 32768] = ~0ull;
    if (gid < 16) misc[gid] = 0;                    // lcount, sqsum, pad
    if (blockIdx.x == 0) {
        if (threadIdx.x < 2) out[OFF_VQ + threadIdx.x] = 0.f;
        if (threadIdx.x < 4) out[OFF_PERP + threadIdx.x] = 0.f;
    }
}

// Single-pass 3-product (hh,hm,mh) MFMA scan — r14 EXACT (empirical optimum:
// 107us, VGPR 64, MfmaUtil 43%; all seven structural deviations r9-r16
// regressed or were neutral; the 2-phase pipe-sum is this kernel's floor).
__global__ __launch_bounds__(TPB) void argmin_kernel(
        const float* __restrict__ z,
        const unsigned short* __restrict__ cbh,
        const unsigned short* __restrict__ cbm,
        const float* __restrict__ cnp4,
        float4* __restrict__ res) {
    __shared__ __align__(16) char lds[2 * BUFSZ];
    // per buffer: [0,8K) lbh | [8K,16K) lbm | [16K,17K) cnp4 quads

    const int t  = threadIdx.x;
    const int l  = t & 63, w = t >> 6;
    const int lc = l & 15, lg = l >> 4;
    const int vb = blockIdx.x >> 2, qh = blockIdx.x & 3;
    const int ebase = qh * QENT;

    union U { bf16x8 v; unsigned short s[8]; };
    U Ah[2][2], Am[2][2];                // on-the-fly 2-split of 32 z rows
#pragma unroll
    for (int set = 0; set < 2; ++set) {
        const float* zp = z + (size_t)(vb * 128 + w * 32 + set * 16 + lc) * DIM + lg * 8;
#pragma unroll
        for (int ks = 0; ks < 2; ++ks)
#pragma unroll
            for (int j = 0; j < 8; ++j) {
                float f = zp[ks * 32 + j];
                unsigned short hh = f2bf(f);
                Ah[set][ks].s[j] = hh;
                Am[set][ks].s[j] = f2bf(f - bf2f(hh));
            }
    }

    float m1[2][4], m2[2][4]; int ix[2][4];
#pragma unroll
    for (int set = 0; set < 2; ++set)
#pragma unroll
        for (int r = 0; r < 4; ++r) {
            m1[set][r] = -INFINITY; m2[set][r] = -INFINITY; ix[set][r] = 0;
        }

    // per-lane LDS read bases: XOR-swizzle folded once; k-step1 = base ^ 64
    const int b0 = (lc * 128 + lg * 16) ^ ((lc & 7) << 4);
    const int b1 = b0 ^ 64;
    const int cb0 = CHUNK * 256 + lc * 16;           // 16K: cnp4 quads

    // stage chunk CH into buffer BUF: linear LDS dest + inverse-swizzled
    // per-lane global source (rule #21; swizzle is an involution).
#define STAGE(CH, BUF) {                                                      \
        const char* sh_ = (const char*)cbh + (size_t)(ebase + (CH) * CHUNK) * 128; \
        const char* sm_ = (const char*)cbm + (size_t)(ebase + (CH) * CHUNK) * 128; \
        _Pragma("unroll")                                                     \
        for (int j = 0; j < 2; ++j) {                                         \
            int lin = (j * 256 + t) * 16;                                     \
            int src = lin ^ (((lin >> 7) & 7) << 4);                          \
            int dstb = lin - l * 16;                                          \
            GLDS16(sh_ + src, (BUF) + dstb);                                  \
            GLDS16(sm_ + src, (BUF) + 8192 + dstb);                           \
        }                                                                     \
        if (t < CHUNK) {                                                      \
            int lin = t * 16;                                                 \
            GLDS16((const char*)cnp4 + (size_t)(ebase + (CH) * CHUNK) * 16 + lin, \
                   (BUF) + 16384 + (lin - l * 16));                           \
        }                                                                     \
    }

    STAGE(0, lds);
    __syncthreads();                                 // vmcnt(0) + barrier

    for (int ch = 0; ch < NCH; ++ch) {
        char* cur = lds + (ch & 1) * BUFSZ;
        if (ch + 1 < NCH) STAGE(ch + 1, lds + ((ch + 1) & 1) * BUFSZ);

        int e0 = ebase + ch * CHUNK + lc;
#pragma unroll
        for (int tile = 0; tile < CHUNK / 16; ++tile) {
            bf16x8 bh0 = *(const bf16x8*)(cur + b0 + tile * 2048);
            bf16x8 bh1 = *(const bf16x8*)(cur + b1 + tile * 2048);
            bf16x8 bm0 = *(const bf16x8*)(cur + 8192 + b0 + tile * 2048);
            bf16x8 bm1 = *(const bf16x8*)(cur + 8192 + b1 + tile * 2048);
            f32x4  c0  = *(const f32x4*)(cur + cb0 + tile * 256);
            int eidx = e0 + tile * 16;
#pragma unroll
            for (int set = 0; set < 2; ++set) {
                f32x4 a = c0;                     // C-init = -||c||^2/2 (free)
                a = __builtin_amdgcn_mfma_f32_16x16x32_bf16(Ah[set][0].v, bh0, a, 0, 0, 0);
                a = __builtin_amdgcn_mfma_f32_16x16x32_bf16(Am[set][0].v, bh0, a, 0, 0, 0);
                a = __builtin_amdgcn_mfma_f32_16x16x32_bf16(Ah[set][0].v, bm0, a, 0, 0, 0);
                a = __builtin_amdgcn_mfma_f32_16x16x32_bf16(Ah[set][1].v, bh1, a, 0, 0, 0);
                a = __builtin_amdgcn_mfma_f32_16x16x32_bf16(Am[set][1].v, bh1, a, 0, 0, 0);
                a = __builtin_amdgcn_mfma_f32_16x16x32_bf16(Ah[set][1].v, bm1, a, 0, 0, 0);
#pragma unroll
                for (int r = 0; r < 4; ++r) {     // D: col=lc, row=lg*4+r (m89)
                    float v = a[r];               // = z.c - ||c||^2/2 exactly
                    m2[set][r] = __builtin_amdgcn_fmed3f(v, m1[set][r], m2[set][r]);
                    if (v > m1[set][r]) { m1[set][r] = v; ix[set][r] = eidx; }
                }
            }
        }
        __syncthreads();   // one barrier/chunk (r14 hazard analysis holds)
    }

    // reduce (max1,idx,max2) across the 16 column-lanes, lowest-idx tiebreak
#pragma unroll
    for (int set = 0; set < 2; ++set)
#pragma unroll
        for (int r = 0; r < 4; ++r) {
            float v1 = m1[set][r], v2 = m2[set][r]; int i1 = ix[set][r];
#pragma unroll
            for (int st = 1; st < 16; st <<= 1) {
                float o1 = __shfl_xor(v1, st, 16);
                float o2 = __shfl_xor(v2, st, 16);
                int   oi = __shfl_xor(i1, st, 16);
                float mn = fminf(v1, o1);
                v2 = fmaxf(fmaxf(v2, o2), mn);
                if (o1 > v1 || (o1 == v1 && oi < i1)) { v1 = o1; i1 = oi; }
            }
            if (lc == 0) {
                int vox = vb * 128 + w * 32 + set * 16 + lg * 4 + r;
                res[(size_t)qh * NVOX + vox] =
                    make_float4(v1, v2, __int_as_float(i1), 0.f);
            }
        }
}

// ---- path B (small ws): combine then gather, res in d_out ----
__global__ void combine_kernel(const float4* __restrict__ res, float* __restrict__ out) {
    int vox = blockIdx.x * blockDim.x + threadIdx.x;
    float v1 = -INFINITY, v2 = -INFINITY; int idx = 0;
#pragma unroll
    for (int h = 0; h < NSPLIT; ++h) {
        float4 t4 = res[(size_t)h * NVOX + vox];
        float a1 = t4.x, a2 = t4.y; int ai = __float_as_int(t4.z);
        float mn = fminf(v1, a1);
        v2 = fmaxf(fmaxf(v2, a2), mn);
        if (a1 > v1) { v1 = a1; idx = ai; }   // strict >: earlier split wins ties
    }
    unsigned flag = (v1 - v2 < CERT_EPS) ? 0x80000000u : 0u;
    ((unsigned*)out)[OFF_IDX + vox] = (unsigned)idx | flag;
}

// r17 gather: 2 threads/row (8 independent float4 gathers each; grid 256
// blocks = 1 block/CU). Keeps r14's deep load-pipelining per thread (the
// property r16's 16-lane version destroyed, -18us) while doubling occupancy.
__global__ void gather_kernel(const float* __restrict__ z, const int* __restrict__ zc,
        const float* __restrict__ cb, float* __restrict__ out,
        unsigned* __restrict__ counts, float* __restrict__ sqsum,
        unsigned* __restrict__ list, unsigned* __restrict__ lcount) {
    int gid = blockIdx.x * TPB + threadIdx.x;
    int vox = gid >> 1, half = gid & 1;
    unsigned pk = ((const unsigned*)out)[OFF_IDX + vox];
    float s = 0.f;
    if (pk & 0x80000000u) {
        if (half == 0) { unsigned pos = atomicAdd(lcount, 1u); list[pos] = vox; }
    } else {
        unsigned idx = pk;
        const float4* crow = (const float4*)(cb + (size_t)idx * DIM) + half * 8;
        const float4* zrow = (const float4*)(z + (size_t)vox * DIM) + half * 8;
        float4* qrow = (float4*)(out + OFF_Q + (size_t)vox * DIM) + half * 8;
#pragma unroll
        for (int i = 0; i < 8; ++i) {
            float4 c4 = crow[i];
            float4 z4 = zrow[i];
            float dx = z4.x - c4.x, dy = z4.y - c4.y;
            float dz = z4.z - c4.z, dw = z4.w - c4.w;
            s += dx * dx + dy * dy + dz * dz + dw * dw;
            qrow[i] = c4;
        }
        if (half == 0) {
            out[OFF_IDX + vox] = (float)idx;
            atomicAdd(&counts[zc[vox * 4] * NUM_EMB + idx], 1u);
        }
    }
#pragma unroll
    for (int o = 32; o > 0; o >>= 1) s += __shfl_down(s, o, 64);
    __shared__ float red[TPB / 64];
    if ((threadIdx.x & 63) == 0) red[threadIdx.x >> 6] = s;
    __syncthreads();
    if (threadIdx.x == 0)
        atomicAdd(sqsum, red[0] + red[1] + red[2] + red[3]);
}

// ---- path A (big ws): fused combine+gather, 2 threads/row, res in ws ----
__global__ void gatherF_kernel(const float* __restrict__ z, const int* __restrict__ zc,
        const float* __restrict__ cb, const float4* __restrict__ res,
        float* __restrict__ out, unsigned* __restrict__ counts,
        float* __restrict__ sqsum, unsigned* __restrict__ list,
        unsigned* __restrict__ lcount) {
    int gid = blockIdx.x * TPB + threadIdx.x;
    int vox = gid >> 1, half = gid & 1;
    float v1 = -INFINITY, v2 = -INFINITY; int idx = 0;
#pragma unroll
    for (int h = 0; h < NSPLIT; ++h) {             // redundant in both halves
        float4 t4 = res[(size_t)h * NVOX + vox];
        float a1 = t4.x, a2 = t4.y; int ai = __float_as_int(t4.z);
        float mn = fminf(v1, a1);
        v2 = fmaxf(fmaxf(v2, a2), mn);
        if (a1 > v1) { v1 = a1; idx = ai; }
    }
    float s = 0.f;
    if (v1 - v2 < CERT_EPS) {
        if (half == 0) { unsigned pos = atomicAdd(lcount, 1u); list[pos] = vox; }
    } else {
        const float4* crow = (const float4*)(cb + (size_t)idx * DIM) + half * 8;
        const float4* zrow = (const float4*)(z + (size_t)vox * DIM) + half * 8;
        float4* qrow = (float4*)(out + OFF_Q + (size_t)vox * DIM) + half * 8;
#pragma unroll
        for (int i = 0; i < 8; ++i) {
            float4 c4 = crow[i];
            float4 z4 = zrow[i];
            float dx = z4.x - c4.x, dy = z4.y - c4.y;
            float dz = z4.z - c4.z, dw = z4.w - c4.w;
            s += dx * dx + dy * dy + dz * dz + dw * dw;
            qrow[i] = c4;
        }
        if (half == 0) {
            out[OFF_IDX + vox] = (float)idx;
            atomicAdd(&counts[zc[vox * 4] * NUM_EMB + idx], 1u);
        }
    }
#pragma unroll
    for (int o = 32; o > 0; o >>= 1) s += __shfl_down(s, o, 64);
    __shared__ float red[TPB / 64];
    if ((threadIdx.x & 63) == 0) red[threadIdx.x >> 6] = s;
    __syncthreads();
    if (threadIdx.x == 0)
        atomicAdd(sqsum, red[0] + red[1] + red[2] + red[3]);
}

// Repair scan: (flagged row, 512-entry chunk) items over 2048 waves;
// coalesced 4-entry groups, x4 interleaved reduce chains; exact f32 dists
// merged via packed (sortable<<32)|idx u64 atomicMin (lowest-idx ties).
__global__ void repair_scan_kernel(const float* __restrict__ z,
        const float* __restrict__ cb, const unsigned* __restrict__ list,
        const unsigned* __restrict__ lcount,
        unsigned long long* __restrict__ merge) {
    int wid = (blockIdx.x * blockDim.x + threadIdx.x) >> 6;
    int l   = threadIdx.x & 63;
    int nw  = (gridDim.x * blockDim.x) >> 6;
    int nitems = (int)*lcount * (NUM_EMB / RCH);
    int sub = l & 15, ent = l >> 4;

    for (int it = wid; it < nitems; it += nw) {
        int k    = it / (NUM_EMB / RCH);
        int base = (it % (NUM_EMB / RCH)) * RCH;
        int vox  = list[k];
        float4 z4 = ((const float4*)(z + (size_t)vox * DIM))[sub];
        float m = INFINITY; int mi = 0;

        for (int g0 = 0; g0 < RCH / 4; g0 += 4) {
            float d[4];
#pragma unroll
            for (int u = 0; u < 4; ++u) {
                int e = base + (g0 + u) * 4 + ent;
                float4 c4 = ((const float4*)(cb + (size_t)e * DIM))[sub];
                float dx = z4.x - c4.x, dy = z4.y - c4.y;
                float dz = z4.z - c4.z, dw = z4.w - c4.w;
                d[u] = fmaf(dx, dx, fmaf(dy, dy, fmaf(dz, dz, dw * dw)));
            }
#pragma unroll
            for (int st = 1; st < 16; st <<= 1)     // 4 independent chains
#pragma unroll
                for (int u = 0; u < 4; ++u) d[u] += __shfl_xor(d[u], st, 16);
#pragma unroll
            for (int u = 0; u < 4; ++u) {
                int e = base + (g0 + u) * 4 + ent;
                if (d[u] < m) { m = d[u]; mi = e; }  // ascending e: lowest-idx
            }
        }
#pragma unroll
        for (int st = 32; st > 0; st >>= 1) {
            float om = __shfl_xor(m, st, 64);
            int   oi = __shfl_xor(mi, st, 64);
            if (om < m || (om == m && oi < mi)) { m = om; mi = oi; }
        }
        if (l == 0) {
            unsigned long long key =
                ((unsigned long long)fmap(m) << 32) | (unsigned)mi;
            atomicMin(&merge[vox], key);
        }
    }
}

// apply repaired argmin: Q row, idx, counts, sqsum for flagged rows
__global__ void repair_apply_kernel(const float* __restrict__ z,
        const int* __restrict__ zc, const float* __restrict__ cb,
        const unsigned* __restrict__ list, const unsigned* __restrict__ lcount,
        const unsigned long long* __restrict__ merge, float* __restrict__ out,
        unsigned* __restrict__ counts, float* __restrict__ sqsum) {
    int wid = (blockIdx.x * blockDim.x + threadIdx.x) >> 6;
    int l   = threadIdx.x & 63;
    int n   = (int)*lcount;
    int nw  = (gridDim.x * blockDim.x) >> 6;
    for (int k = wid; k < n; k += nw) {
        int vox = list[k];
        int mi  = (int)(merge[vox] & 0xFFFFFFFFull);
        float cv = cb[(size_t)mi * DIM + l];
        float zv = z[(size_t)vox * DIM + l];
        out[OFF_Q + (size_t)vox * DIM + l] = cv;
        float df = zv - cv;
        float s = df * df;
#pragma unroll
        for (int st = 32; st > 0; st >>= 1) s += __shfl_xor(s, st, 64);
        if (l == 0) {
            out[OFF_IDX + vox] = (float)mi;
            atomicAdd(&counts[zc[vox * 4] * NUM_EMB + mi], 1u);
            atomicAdd(sqsum, s);
        }
    }
}

// per-batch entropy/unique + fused finalize via atomicAdd on zeroed scalars
__global__ void stats_final_kernel(const unsigned* __restrict__ counts,
                                   const float* __restrict__ sqsum,
                                   float* __restrict__ out) {
    int b = blockIdx.x;
    const unsigned* c = counts + b * NUM_EMB;

    __shared__ float sred[TPB / 64];
    float nf = 0.f;
    for (int i = threadIdx.x; i < NUM_EMB; i += TPB) nf += (float)c[i];
#pragma unroll
    for (int o = 32; o > 0; o >>= 1) nf += __shfl_down(nf, o, 64);
    if ((threadIdx.x & 63) == 0) sred[threadIdx.x >> 6] = nf;
    __syncthreads();
    float n = sred[0] + sred[1] + sred[2] + sred[3];
    __syncthreads();

    float ent = 0.f, uniq = 0.f;
    for (int i = threadIdx.x; i < NUM_EMB; i += TPB) {
        unsigned ci = c[i];
        if (ci) {
            float p = (float)ci / n;
            ent -= p * logf(p + 1e-10f);
            uniq += 1.f;
        }
    }
#pragma unroll
    for (int o = 32; o > 0; o >>= 1) {
        ent  += __shfl_down(ent, o, 64);
        uniq += __shfl_down(uniq, o, 64);
    }
    __shared__ float e4[TPB / 64], u4[TPB / 64];
    if ((threadIdx.x & 63) == 0) { e4[threadIdx.x >> 6] = ent; u4[threadIdx.x >> 6] = uniq; }
    __syncthreads();
    if (threadIdx.x == 0) {
        float eb = e4[0] + e4[1] + e4[2] + e4[3];
        float ub = u4[0] + u4[1] + u4[2] + u4[3];
        atomicAdd(&out[OFF_ENT],  eb * 0.25f);
        atomicAdd(&out[OFF_PERP], expf(eb) * 0.25f);
        atomicAdd(&out[OFF_UNIQ], ub * 0.25f);
        atomicAdd(&out[OFF_UTIL], ub * (100.f / (4.f * NUM_EMB)));
        if (b == 0) {
            float loss = *sqsum / (float)((size_t)NVOX * DIM);
            out[OFF_VQ]   = loss;
            out[OFF_COMM] = loss;
        }
    }
}

extern "C" void kernel_launch(void* const* d_in, const int* in_sizes, int n_in,
                              void* d_out, int out_size, void* d_ws, size_t ws_size,
                              hipStream_t stream) {
    const float* z  = (const float*)d_in[0];
    const int*   zc = (const int*)d_in[1];
    const float* cb = (const float*)d_in[2];
    float* out = (float*)d_out;
    char* ws = (char*)d_ws;

    // d_out scratch: cbh 1MB | cbm 1MB at Q floats [0, 524288).
    unsigned short* cbh = (unsigned short*)out;
    unsigned short* cbm = cbh + NUM_EMB * DIM;

    unsigned* counts = (unsigned*)ws;                       // 131072 B
    unsigned* list   = (unsigned*)(ws + 131072);            // 131072 B
    unsigned* misc   = (unsigned*)(ws + 262144);            // 64 B
    unsigned* lcount = misc;
    float*    sqsum  = (float*)(ws + 262148);
    float*    cnp4   = (float*)(ws + 262208);               // 131072 B
    unsigned long long* merge = (unsigned long long*)(ws + 393280); // 262144 B
    // path A: res in ws (2MB) -> fused combine+gather
    size_t res_ws_off = 655424;
    bool bigws = ws_size >= res_ws_off + (size_t)NSPLIT * NVOX * 16;
    float4* res = bigws ? (float4*)(ws + res_ws_off)
                        : (float4*)(out + 524288);  // path B: floats [524288,1048576)

    prep_kernel<<<NUM_EMB / 4, TPB, 0, stream>>>(cb, cbh, cbm, cnp4, counts,
                                                 misc, merge, out);
    argmin_kernel<<<(NVOX / 128) * NSPLIT, TPB, 0, stream>>>(z, cbh, cbm, cnp4, res);
    if (bigws) {
        gatherF_kernel<<<(NVOX * 2) / TPB, TPB, 0, stream>>>(z, zc, cb, res, out,
                                                             counts, sqsum, list, lcount);
    } else {
        combine_kernel<<<NVOX / TPB, TPB, 0, stream>>>(res, out);
        gather_kernel<<<(NVOX * 2) / TPB, TPB, 0, stream>>>(z, zc, cb, out, counts,
                                                            sqsum, list, lcount);
    }
    repair_scan_kernel<<<512, TPB, 0, stream>>>(z, cb, list, lcount, merge);
    repair_apply_kernel<<<64, TPB, 0, stream>>>(z, zc, cb, list, lcount, merge,
                                                out, counts, sqsum);
    stats_final_kernel<<<NBATCH, TPB, 0, stream>>>(counts, sqsum, out);
}

// Round 18
// 185.820 us; speedup vs baseline: 1.1538x; 1.0429x over previous
//
#include <hip/hip_runtime.h>
#include <math.h>

#define NUM_EMB 8192
#define DIM     64
#define NBATCH  4
#define TPB     256
#define STPB    1024              // stats kernel: 16 waves/block (r18)
#define NVOX    32768
#define NSPLIT  4                 // codebook splits (quarter per block)
#define QENT    (NUM_EMB / NSPLIT)
#define CHUNK   64                // entries per buffer (dbuf LDS = 34816B)
#define NCH     (QENT / CHUNK)    // 32 chunks
#define BUFSZ   (CHUNK * 128 * 2 + CHUNK * 16)  // lbh 8K | lbm 8K | cnp4 1K
#define CERT_EPS 0.015f           // v-space gap threshold (err bound ~3.2e-3)
#define RCH     512               // repair: entries per (row,chunk) work item

// output layout (f32, concatenated in return order)
#define OFF_Q     0            // 32768*64
#define OFF_VQ    2097152
#define OFF_COMM  2097153
#define OFF_IDX   2097154      // 32768
#define OFF_PERP  2129922
#define OFF_ENT   2129923
#define OFF_UNIQ  2129924
#define OFF_UTIL  2129925

typedef __bf16 bf16x8 __attribute__((ext_vector_type(8)));
typedef float  f32x4  __attribute__((ext_vector_type(4)));

// async global->LDS, 16B per lane; LDS dest is wave-uniform base + lane*16
#define GLDS16(SRC, DST) __builtin_amdgcn_global_load_lds(                    \
        (const __attribute__((address_space(1))) void*)(SRC),                 \
        (__attribute__((address_space(3))) void*)(DST), 16, 0, 0)

__device__ __forceinline__ unsigned short f2bf(float f) {   // RNE f32->bf16
    unsigned u = __float_as_uint(f);
    unsigned r = u + 0x7FFFu + ((u >> 16) & 1u);
    return (unsigned short)(r >> 16);
}
__device__ __forceinline__ float bf2f(unsigned short h) {
    return __uint_as_float(((unsigned)h) << 16);
}
// monotone float -> sortable uint (non-NaN)
__device__ __forceinline__ unsigned fmap(float f) {
    unsigned u = __float_as_uint(f);
    return (u & 0x80000000u) ? ~u : (u | 0x80000000u);
}

// prep: bf16 2-split of codebook, replicated -||c||^2/2 quads, all scratch
// init, scalar-output zeroing (poisoned 0xAA; stats uses atomicAdd).
__global__ void prep_kernel(const float* __restrict__ cb,
                            unsigned short* __restrict__ cbh,
                            unsigned short* __restrict__ cbm,
                            float* __restrict__ cnp4,
                            unsigned* __restrict__ counts,
                            unsigned* __restrict__ misc,
                            unsigned long long* __restrict__ merge,
                            float* __restrict__ out) {
    int row = blockIdx.x * 4 + (threadIdx.x >> 6);
    int l   = threadIdx.x & 63;
    float f = cb[row * DIM + l];
    unsigned short hh = f2bf(f); float r1 = f - bf2f(hh);
    cbh[row * DIM + l] = hh;
    cbm[row * DIM + l] = f2bf(r1);
    float s = f * f;
#pragma unroll
    for (int o = 32; o > 0; o >>= 1) s += __shfl_xor(s, o, 64);
    if (l < 4) cnp4[row * 4 + l] = -0.5f * s;      // replicated x4 -> b128 C-init

    int gid = blockIdx.x * TPB + threadIdx.x;       // 0..524287
    if (gid < NBATCH * NUM_EMB) counts[gid] = 0;
    if (gid >= 32768 && gid < 65536) merge[gid - 32768] = ~0ull;
    if (gid < 16) misc[gid] = 0;                    // lcount, sqsum, pad
    if (blockIdx.x == 0) {
        if (threadIdx.x < 2) out[OFF_VQ + threadIdx.x] = 0.f;
        if (threadIdx.x < 4) out[OFF_PERP + threadIdx.x] = 0.f;
    }
}

// Single-pass 3-product (hh,hm,mh) MFMA scan — r14 EXACT (empirical optimum:
// 107us, VGPR 64, MfmaUtil 43%; nine structural deviations r9-r17 regressed
// or were neutral; the 2-phase pipe-sum is this kernel's floor).
__global__ __launch_bounds__(TPB) void argmin_kernel(
        const float* __restrict__ z,
        const unsigned short* __restrict__ cbh,
        const unsigned short* __restrict__ cbm,
        const float* __restrict__ cnp4,
        float4* __restrict__ res) {
    __shared__ __align__(16) char lds[2 * BUFSZ];
    // per buffer: [0,8K) lbh | [8K,16K) lbm | [16K,17K) cnp4 quads

    const int t  = threadIdx.x;
    const int l  = t & 63, w = t >> 6;
    const int lc = l & 15, lg = l >> 4;
    const int vb = blockIdx.x >> 2, qh = blockIdx.x & 3;
    const int ebase = qh * QENT;

    union U { bf16x8 v; unsigned short s[8]; };
    U Ah[2][2], Am[2][2];                // on-the-fly 2-split of 32 z rows
#pragma unroll
    for (int set = 0; set < 2; ++set) {
        const float* zp = z + (size_t)(vb * 128 + w * 32 + set * 16 + lc) * DIM + lg * 8;
#pragma unroll
        for (int ks = 0; ks < 2; ++ks)
#pragma unroll
            for (int j = 0; j < 8; ++j) {
                float f = zp[ks * 32 + j];
                unsigned short hh = f2bf(f);
                Ah[set][ks].s[j] = hh;
                Am[set][ks].s[j] = f2bf(f - bf2f(hh));
            }
    }

    float m1[2][4], m2[2][4]; int ix[2][4];
#pragma unroll
    for (int set = 0; set < 2; ++set)
#pragma unroll
        for (int r = 0; r < 4; ++r) {
            m1[set][r] = -INFINITY; m2[set][r] = -INFINITY; ix[set][r] = 0;
        }

    // per-lane LDS read bases: XOR-swizzle folded once; k-step1 = base ^ 64
    const int b0 = (lc * 128 + lg * 16) ^ ((lc & 7) << 4);
    const int b1 = b0 ^ 64;
    const int cb0 = CHUNK * 256 + lc * 16;           // 16K: cnp4 quads

    // stage chunk CH into buffer BUF: linear LDS dest + inverse-swizzled
    // per-lane global source (rule #21; swizzle is an involution).
#define STAGE(CH, BUF) {                                                      \
        const char* sh_ = (const char*)cbh + (size_t)(ebase + (CH) * CHUNK) * 128; \
        const char* sm_ = (const char*)cbm + (size_t)(ebase + (CH) * CHUNK) * 128; \
        _Pragma("unroll")                                                     \
        for (int j = 0; j < 2; ++j) {                                         \
            int lin = (j * 256 + t) * 16;                                     \
            int src = lin ^ (((lin >> 7) & 7) << 4);                          \
            int dstb = lin - l * 16;                                          \
            GLDS16(sh_ + src, (BUF) + dstb);                                  \
            GLDS16(sm_ + src, (BUF) + 8192 + dstb);                           \
        }                                                                     \
        if (t < CHUNK) {                                                      \
            int lin = t * 16;                                                 \
            GLDS16((const char*)cnp4 + (size_t)(ebase + (CH) * CHUNK) * 16 + lin, \
                   (BUF) + 16384 + (lin - l * 16));                           \
        }                                                                     \
    }

    STAGE(0, lds);
    __syncthreads();                                 // vmcnt(0) + barrier

    for (int ch = 0; ch < NCH; ++ch) {
        char* cur = lds + (ch & 1) * BUFSZ;
        if (ch + 1 < NCH) STAGE(ch + 1, lds + ((ch + 1) & 1) * BUFSZ);

        int e0 = ebase + ch * CHUNK + lc;
#pragma unroll
        for (int tile = 0; tile < CHUNK / 16; ++tile) {
            bf16x8 bh0 = *(const bf16x8*)(cur + b0 + tile * 2048);
            bf16x8 bh1 = *(const bf16x8*)(cur + b1 + tile * 2048);
            bf16x8 bm0 = *(const bf16x8*)(cur + 8192 + b0 + tile * 2048);
            bf16x8 bm1 = *(const bf16x8*)(cur + 8192 + b1 + tile * 2048);
            f32x4  c0  = *(const f32x4*)(cur + cb0 + tile * 256);
            int eidx = e0 + tile * 16;
#pragma unroll
            for (int set = 0; set < 2; ++set) {
                f32x4 a = c0;                     // C-init = -||c||^2/2 (free)
                a = __builtin_amdgcn_mfma_f32_16x16x32_bf16(Ah[set][0].v, bh0, a, 0, 0, 0);
                a = __builtin_amdgcn_mfma_f32_16x16x32_bf16(Am[set][0].v, bh0, a, 0, 0, 0);
                a = __builtin_amdgcn_mfma_f32_16x16x32_bf16(Ah[set][0].v, bm0, a, 0, 0, 0);
                a = __builtin_amdgcn_mfma_f32_16x16x32_bf16(Ah[set][1].v, bh1, a, 0, 0, 0);
                a = __builtin_amdgcn_mfma_f32_16x16x32_bf16(Am[set][1].v, bh1, a, 0, 0, 0);
                a = __builtin_amdgcn_mfma_f32_16x16x32_bf16(Ah[set][1].v, bm1, a, 0, 0, 0);
#pragma unroll
                for (int r = 0; r < 4; ++r) {     // D: col=lc, row=lg*4+r (m89)
                    float v = a[r];               // = z.c - ||c||^2/2 exactly
                    m2[set][r] = __builtin_amdgcn_fmed3f(v, m1[set][r], m2[set][r]);
                    if (v > m1[set][r]) { m1[set][r] = v; ix[set][r] = eidx; }
                }
            }
        }
        __syncthreads();   // one barrier/chunk (r14 hazard analysis holds)
    }

    // reduce (max1,idx,max2) across the 16 column-lanes, lowest-idx tiebreak
#pragma unroll
    for (int set = 0; set < 2; ++set)
#pragma unroll
        for (int r = 0; r < 4; ++r) {
            float v1 = m1[set][r], v2 = m2[set][r]; int i1 = ix[set][r];
#pragma unroll
            for (int st = 1; st < 16; st <<= 1) {
                float o1 = __shfl_xor(v1, st, 16);
                float o2 = __shfl_xor(v2, st, 16);
                int   oi = __shfl_xor(i1, st, 16);
                float mn = fminf(v1, o1);
                v2 = fmaxf(fmaxf(v2, o2), mn);
                if (o1 > v1 || (o1 == v1 && oi < i1)) { v1 = o1; i1 = oi; }
            }
            if (lc == 0) {
                int vox = vb * 128 + w * 32 + set * 16 + lg * 4 + r;
                res[(size_t)qh * NVOX + vox] =
                    make_float4(v1, v2, __int_as_float(i1), 0.f);
            }
        }
}

// ---- path B (small ws): combine then gather, res in d_out ----
__global__ void combine_kernel(const float4* __restrict__ res, float* __restrict__ out) {
    int vox = blockIdx.x * blockDim.x + threadIdx.x;
    float v1 = -INFINITY, v2 = -INFINITY; int idx = 0;
#pragma unroll
    for (int h = 0; h < NSPLIT; ++h) {
        float4 t4 = res[(size_t)h * NVOX + vox];
        float a1 = t4.x, a2 = t4.y; int ai = __float_as_int(t4.z);
        float mn = fminf(v1, a1);
        v2 = fmaxf(fmaxf(v2, a2), mn);
        if (a1 > v1) { v1 = a1; idx = ai; }   // strict >: earlier split wins ties
    }
    unsigned flag = (v1 - v2 < CERT_EPS) ? 0x80000000u : 0u;
    ((unsigned*)out)[OFF_IDX + vox] = (unsigned)idx | flag;
}

// r18 gather: 4 threads/row (4 independent float4 gathers each; grid 512
// blocks = 2/CU). Midpoint of the r14(1t)/r17(2t, best)/r16(16t, regressed)
// ILP-vs-TLP sweep.
__global__ void gather_kernel(const float* __restrict__ z, const int* __restrict__ zc,
        const float* __restrict__ cb, float* __restrict__ out,
        unsigned* __restrict__ counts, float* __restrict__ sqsum,
        unsigned* __restrict__ list, unsigned* __restrict__ lcount) {
    int gid = blockIdx.x * TPB + threadIdx.x;
    int vox = gid >> 2, q = gid & 3;
    unsigned pk = ((const unsigned*)out)[OFF_IDX + vox];
    float s = 0.f;
    if (pk & 0x80000000u) {
        if (q == 0) { unsigned pos = atomicAdd(lcount, 1u); list[pos] = vox; }
    } else {
        unsigned idx = pk;
        const float4* crow = (const float4*)(cb + (size_t)idx * DIM) + q * 4;
        const float4* zrow = (const float4*)(z + (size_t)vox * DIM) + q * 4;
        float4* qrow = (float4*)(out + OFF_Q + (size_t)vox * DIM) + q * 4;
#pragma unroll
        for (int i = 0; i < 4; ++i) {
            float4 c4 = crow[i];
            float4 z4 = zrow[i];
            float dx = z4.x - c4.x, dy = z4.y - c4.y;
            float dz = z4.z - c4.z, dw = z4.w - c4.w;
            s += dx * dx + dy * dy + dz * dz + dw * dw;
            qrow[i] = c4;
        }
        if (q == 0) {
            out[OFF_IDX + vox] = (float)idx;
            atomicAdd(&counts[zc[vox * 4] * NUM_EMB + idx], 1u);
        }
    }
#pragma unroll
    for (int o = 32; o > 0; o >>= 1) s += __shfl_down(s, o, 64);
    __shared__ float red[TPB / 64];
    if ((threadIdx.x & 63) == 0) red[threadIdx.x >> 6] = s;
    __syncthreads();
    if (threadIdx.x == 0)
        atomicAdd(sqsum, red[0] + red[1] + red[2] + red[3]);
}

// ---- path A (big ws): fused combine+gather, 4 threads/row, res in ws ----
__global__ void gatherF_kernel(const float* __restrict__ z, const int* __restrict__ zc,
        const float* __restrict__ cb, const float4* __restrict__ res,
        float* __restrict__ out, unsigned* __restrict__ counts,
        float* __restrict__ sqsum, unsigned* __restrict__ list,
        unsigned* __restrict__ lcount) {
    int gid = blockIdx.x * TPB + threadIdx.x;
    int vox = gid >> 2, q = gid & 3;
    float v1 = -INFINITY, v2 = -INFINITY; int idx = 0;
#pragma unroll
    for (int h = 0; h < NSPLIT; ++h) {             // redundant in all quarters
        float4 t4 = res[(size_t)h * NVOX + vox];
        float a1 = t4.x, a2 = t4.y; int ai = __float_as_int(t4.z);
        float mn = fminf(v1, a1);
        v2 = fmaxf(fmaxf(v2, a2), mn);
        if (a1 > v1) { v1 = a1; idx = ai; }
    }
    float s = 0.f;
    if (v1 - v2 < CERT_EPS) {
        if (q == 0) { unsigned pos = atomicAdd(lcount, 1u); list[pos] = vox; }
    } else {
        const float4* crow = (const float4*)(cb + (size_t)idx * DIM) + q * 4;
        const float4* zrow = (const float4*)(z + (size_t)vox * DIM) + q * 4;
        float4* qrow = (float4*)(out + OFF_Q + (size_t)vox * DIM) + q * 4;
#pragma unroll
        for (int i = 0; i < 4; ++i) {
            float4 c4 = crow[i];
            float4 z4 = zrow[i];
            float dx = z4.x - c4.x, dy = z4.y - c4.y;
            float dz = z4.z - c4.z, dw = z4.w - c4.w;
            s += dx * dx + dy * dy + dz * dz + dw * dw;
            qrow[i] = c4;
        }
        if (q == 0) {
            out[OFF_IDX + vox] = (float)idx;
            atomicAdd(&counts[zc[vox * 4] * NUM_EMB + idx], 1u);
        }
    }
#pragma unroll
    for (int o = 32; o > 0; o >>= 1) s += __shfl_down(s, o, 64);
    __shared__ float red[TPB / 64];
    if ((threadIdx.x & 63) == 0) red[threadIdx.x >> 6] = s;
    __syncthreads();
    if (threadIdx.x == 0)
        atomicAdd(sqsum, red[0] + red[1] + red[2] + red[3]);
}

// Repair scan: (flagged row, 512-entry chunk) items over 2048 waves;
// coalesced 4-entry groups, x4 interleaved reduce chains; exact f32 dists
// merged via packed (sortable<<32)|idx u64 atomicMin (lowest-idx ties).
__global__ void repair_scan_kernel(const float* __restrict__ z,
        const float* __restrict__ cb, const unsigned* __restrict__ list,
        const unsigned* __restrict__ lcount,
        unsigned long long* __restrict__ merge) {
    int wid = (blockIdx.x * blockDim.x + threadIdx.x) >> 6;
    int l   = threadIdx.x & 63;
    int nw  = (gridDim.x * blockDim.x) >> 6;
    int nitems = (int)*lcount * (NUM_EMB / RCH);
    int sub = l & 15, ent = l >> 4;

    for (int it = wid; it < nitems; it += nw) {
        int k    = it / (NUM_EMB / RCH);
        int base = (it % (NUM_EMB / RCH)) * RCH;
        int vox  = list[k];
        float4 z4 = ((const float4*)(z + (size_t)vox * DIM))[sub];
        float m = INFINITY; int mi = 0;

        for (int g0 = 0; g0 < RCH / 4; g0 += 4) {
            float d[4];
#pragma unroll
            for (int u = 0; u < 4; ++u) {
                int e = base + (g0 + u) * 4 + ent;
                float4 c4 = ((const float4*)(cb + (size_t)e * DIM))[sub];
                float dx = z4.x - c4.x, dy = z4.y - c4.y;
                float dz = z4.z - c4.z, dw = z4.w - c4.w;
                d[u] = fmaf(dx, dx, fmaf(dy, dy, fmaf(dz, dz, dw * dw)));
            }
#pragma unroll
            for (int st = 1; st < 16; st <<= 1)     // 4 independent chains
#pragma unroll
                for (int u = 0; u < 4; ++u) d[u] += __shfl_xor(d[u], st, 16);
#pragma unroll
            for (int u = 0; u < 4; ++u) {
                int e = base + (g0 + u) * 4 + ent;
                if (d[u] < m) { m = d[u]; mi = e; }  // ascending e: lowest-idx
            }
        }
#pragma unroll
        for (int st = 32; st > 0; st >>= 1) {
            float om = __shfl_xor(m, st, 64);
            int   oi = __shfl_xor(mi, st, 64);
            if (om < m || (om == m && oi < mi)) { m = om; mi = oi; }
        }
        if (l == 0) {
            unsigned long long key =
                ((unsigned long long)fmap(m) << 32) | (unsigned)mi;
            atomicMin(&merge[vox], key);
        }
    }
}

// apply repaired argmin: Q row, idx, counts, sqsum for flagged rows
__global__ void repair_apply_kernel(const float* __restrict__ z,
        const int* __restrict__ zc, const float* __restrict__ cb,
        const unsigned* __restrict__ list, const unsigned* __restrict__ lcount,
        const unsigned long long* __restrict__ merge, float* __restrict__ out,
        unsigned* __restrict__ counts, float* __restrict__ sqsum) {
    int wid = (blockIdx.x * blockDim.x + threadIdx.x) >> 6;
    int l   = threadIdx.x & 63;
    int n   = (int)*lcount;
    int nw  = (gridDim.x * blockDim.x) >> 6;
    for (int k = wid; k < n; k += nw) {
        int vox = list[k];
        int mi  = (int)(merge[vox] & 0xFFFFFFFFull);
        float cv = cb[(size_t)mi * DIM + l];
        float zv = z[(size_t)vox * DIM + l];
        out[OFF_Q + (size_t)vox * DIM + l] = cv;
        float df = zv - cv;
        float s = df * df;
#pragma unroll
        for (int st = 32; st > 0; st >>= 1) s += __shfl_xor(s, st, 64);
        if (l == 0) {
            out[OFF_IDX + vox] = (float)mi;
            atomicAdd(&counts[zc[vox * 4] * NUM_EMB + mi], 1u);
            atomicAdd(sqsum, s);
        }
    }
}

// per-batch entropy/unique + fused finalize; r18: 1024 threads/block
// (16 waves, was 4) -> 4x fewer serial iterations on the 4-block kernel.
__global__ __launch_bounds__(STPB) void stats_final_kernel(
        const unsigned* __restrict__ counts,
        const float* __restrict__ sqsum,
        float* __restrict__ out) {
    int b = blockIdx.x;
    const unsigned* c = counts + b * NUM_EMB;

    __shared__ float sred[STPB / 64];
    float nf = 0.f;
    for (int i = threadIdx.x; i < NUM_EMB; i += STPB) nf += (float)c[i];
#pragma unroll
    for (int o = 32; o > 0; o >>= 1) nf += __shfl_down(nf, o, 64);
    if ((threadIdx.x & 63) == 0) sred[threadIdx.x >> 6] = nf;
    __syncthreads();
    float n = 0.f;
#pragma unroll
    for (int i = 0; i < STPB / 64; ++i) n += sred[i];
    __syncthreads();

    float ent = 0.f, uniq = 0.f;
    for (int i = threadIdx.x; i < NUM_EMB; i += STPB) {
        unsigned ci = c[i];
        if (ci) {
            float p = (float)ci / n;
            ent -= p * logf(p + 1e-10f);
            uniq += 1.f;
        }
    }
#pragma unroll
    for (int o = 32; o > 0; o >>= 1) {
        ent  += __shfl_down(ent, o, 64);
        uniq += __shfl_down(uniq, o, 64);
    }
    __shared__ float e4[STPB / 64], u4[STPB / 64];
    if ((threadIdx.x & 63) == 0) { e4[threadIdx.x >> 6] = ent; u4[threadIdx.x >> 6] = uniq; }
    __syncthreads();
    if (threadIdx.x == 0) {
        float eb = 0.f, ub = 0.f;
#pragma unroll
        for (int i = 0; i < STPB / 64; ++i) { eb += e4[i]; ub += u4[i]; }
        atomicAdd(&out[OFF_ENT],  eb * 0.25f);
        atomicAdd(&out[OFF_PERP], expf(eb) * 0.25f);
        atomicAdd(&out[OFF_UNIQ], ub * 0.25f);
        atomicAdd(&out[OFF_UTIL], ub * (100.f / (4.f * NUM_EMB)));
        if (b == 0) {
            float loss = *sqsum / (float)((size_t)NVOX * DIM);
            out[OFF_VQ]   = loss;
            out[OFF_COMM] = loss;
        }
    }
}

extern "C" void kernel_launch(void* const* d_in, const int* in_sizes, int n_in,
                              void* d_out, int out_size, void* d_ws, size_t ws_size,
                              hipStream_t stream) {
    const float* z  = (const float*)d_in[0];
    const int*   zc = (const int*)d_in[1];
    const float* cb = (const float*)d_in[2];
    float* out = (float*)d_out;
    char* ws = (char*)d_ws;

    // d_out scratch: cbh 1MB | cbm 1MB at Q floats [0, 524288).
    unsigned short* cbh = (unsigned short*)out;
    unsigned short* cbm = cbh + NUM_EMB * DIM;

    unsigned* counts = (unsigned*)ws;                       // 131072 B
    unsigned* list   = (unsigned*)(ws + 131072);            // 131072 B
    unsigned* misc   = (unsigned*)(ws + 262144);            // 64 B
    unsigned* lcount = misc;
    float*    sqsum  = (float*)(ws + 262148);
    float*    cnp4   = (float*)(ws + 262208);               // 131072 B
    unsigned long long* merge = (unsigned long long*)(ws + 393280); // 262144 B
    // path A: res in ws (2MB) -> fused combine+gather
    size_t res_ws_off = 655424;
    bool bigws = ws_size >= res_ws_off + (size_t)NSPLIT * NVOX * 16;
    float4* res = bigws ? (float4*)(ws + res_ws_off)
                        : (float4*)(out + 524288);  // path B: floats [524288,1048576)

    prep_kernel<<<NUM_EMB / 4, TPB, 0, stream>>>(cb, cbh, cbm, cnp4, counts,
                                                 misc, merge, out);
    argmin_kernel<<<(NVOX / 128) * NSPLIT, TPB, 0, stream>>>(z, cbh, cbm, cnp4, res);
    if (bigws) {
        gatherF_kernel<<<(NVOX * 4) / TPB, TPB, 0, stream>>>(z, zc, cb, res, out,
                                                             counts, sqsum, list, lcount);
    } else {
        combine_kernel<<<NVOX / TPB, TPB, 0, stream>>>(res, out);
        gather_kernel<<<(NVOX * 4) / TPB, TPB, 0, stream>>>(z, zc, cb, out, counts,
                                                            sqsum, list, lcount);
    }
    repair_scan_kernel<<<512, TPB, 0, stream>>>(z, cb, list, lcount, merge);
    repair_apply_kernel<<<64, TPB, 0, stream>>>(z, zc, cb, list, lcount, merge,
                                                out, counts, sqsum);
    stats_final_kernel<<<NBATCH, STPB, 0, stream>>>(counts, sqsum, out);
}

// Round 19
// 172.469 us; speedup vs baseline: 1.2432x; 1.0774x over previous
//
#include <hip/hip_runtime.h>
#include <math.h>

#define NUM_EMB 8192
#define DIM     64
#define NBATCH  4
#define TPB     256
#define STPB    1024              // stats kernel: 16 waves/block
#define NVOX    32768
#define NSPLIT  4                 // codebook splits (quarter per block)
#define QENT    (NUM_EMB / NSPLIT)
#define CHUNK   64                // entries per buffer (dbuf LDS = 34816B)
#define NCH     (QENT / CHUNK)    // 32 chunks
#define BUFSZ   (CHUNK * 128 * 2 + CHUNK * 16)  // lbh 8K | lbm 8K | cnp4 1K
#define CERT_EPS 0.015f           // v-space gap threshold (err bound ~3.2e-3)
#define RCH     512               // repair: entries per (row,chunk) work item

// output layout (f32, concatenated in return order)
#define OFF_Q     0            // 32768*64
#define OFF_VQ    2097152
#define OFF_COMM  2097153
#define OFF_IDX   2097154      // 32768
#define OFF_PERP  2129922
#define OFF_ENT   2129923
#define OFF_UNIQ  2129924
#define OFF_UTIL  2129925

typedef __bf16 bf16x8 __attribute__((ext_vector_type(8)));
typedef float  f32x4  __attribute__((ext_vector_type(4)));

// async global->LDS, 16B per lane; LDS dest is wave-uniform base + lane*16
#define GLDS16(SRC, DST) __builtin_amdgcn_global_load_lds(                    \
        (const __attribute__((address_space(1))) void*)(SRC),                 \
        (__attribute__((address_space(3))) void*)(DST), 16, 0, 0)

__device__ __forceinline__ unsigned short f2bf(float f) {   // RNE f32->bf16
    unsigned u = __float_as_uint(f);
    unsigned r = u + 0x7FFFu + ((u >> 16) & 1u);
    return (unsigned short)(r >> 16);
}
__device__ __forceinline__ float bf2f(unsigned short h) {
    return __uint_as_float(((unsigned)h) << 16);
}
// monotone float -> sortable uint (non-NaN)
__device__ __forceinline__ unsigned fmap(float f) {
    unsigned u = __float_as_uint(f);
    return (u & 0x80000000u) ? ~u : (u | 0x80000000u);
}

// prep: bf16 2-split of codebook, replicated -||c||^2/2 quads, all scratch
// init, scalar-output zeroing (poisoned 0xAA; stats uses atomicAdd).
__global__ void prep_kernel(const float* __restrict__ cb,
                            unsigned short* __restrict__ cbh,
                            unsigned short* __restrict__ cbm,
                            float* __restrict__ cnp4,
                            unsigned* __restrict__ counts,
                            unsigned* __restrict__ misc,
                            unsigned long long* __restrict__ merge,
                            float* __restrict__ out) {
    int row = blockIdx.x * 4 + (threadIdx.x >> 6);
    int l   = threadIdx.x & 63;
    float f = cb[row * DIM + l];
    unsigned short hh = f2bf(f); float r1 = f - bf2f(hh);
    cbh[row * DIM + l] = hh;
    cbm[row * DIM + l] = f2bf(r1);
    float s = f * f;
#pragma unroll
    for (int o = 32; o > 0; o >>= 1) s += __shfl_xor(s, o, 64);
    if (l < 4) cnp4[row * 4 + l] = -0.5f * s;      // replicated x4 -> b128 C-init

    int gid = blockIdx.x * TPB + threadIdx.x;       // 0..524287
    if (gid < NBATCH * NUM_EMB) counts[gid] = 0;
    if (gid >= 32768 && gid < 65536) merge[gid - 32768] = ~0ull;
    if (gid < 16) misc[gid] = 0;                    // lcount, sqsum, pad
    if (blockIdx.x == 0) {
        if (threadIdx.x < 2) out[OFF_VQ + threadIdx.x] = 0.f;
        if (threadIdx.x < 4) out[OFF_PERP + threadIdx.x] = 0.f;
    }
}

// Single-pass 3-product (hh,hm,mh) MFMA scan — r14 EXACT (empirical optimum:
// 107us, VGPR 64, MfmaUtil 43%; ten structural probes r9-r18 regressed or
// were neutral; the 2-phase pipe-sum is this kernel's floor).
__global__ __launch_bounds__(TPB) void argmin_kernel(
        const float* __restrict__ z,
        const unsigned short* __restrict__ cbh,
        const unsigned short* __restrict__ cbm,
        const float* __restrict__ cnp4,
        float4* __restrict__ res) {
    __shared__ __align__(16) char lds[2 * BUFSZ];
    // per buffer: [0,8K) lbh | [8K,16K) lbm | [16K,17K) cnp4 quads

    const int t  = threadIdx.x;
    const int l  = t & 63, w = t >> 6;
    const int lc = l & 15, lg = l >> 4;
    const int vb = blockIdx.x >> 2, qh = blockIdx.x & 3;
    const int ebase = qh * QENT;

    union U { bf16x8 v; unsigned short s[8]; };
    U Ah[2][2], Am[2][2];                // on-the-fly 2-split of 32 z rows
#pragma unroll
    for (int set = 0; set < 2; ++set) {
        const float* zp = z + (size_t)(vb * 128 + w * 32 + set * 16 + lc) * DIM + lg * 8;
#pragma unroll
        for (int ks = 0; ks < 2; ++ks)
#pragma unroll
            for (int j = 0; j < 8; ++j) {
                float f = zp[ks * 32 + j];
                unsigned short hh = f2bf(f);
                Ah[set][ks].s[j] = hh;
                Am[set][ks].s[j] = f2bf(f - bf2f(hh));
            }
    }

    float m1[2][4], m2[2][4]; int ix[2][4];
#pragma unroll
    for (int set = 0; set < 2; ++set)
#pragma unroll
        for (int r = 0; r < 4; ++r) {
            m1[set][r] = -INFINITY; m2[set][r] = -INFINITY; ix[set][r] = 0;
        }

    // per-lane LDS read bases: XOR-swizzle folded once; k-step1 = base ^ 64
    const int b0 = (lc * 128 + lg * 16) ^ ((lc & 7) << 4);
    const int b1 = b0 ^ 64;
    const int cb0 = CHUNK * 256 + lc * 16;           // 16K: cnp4 quads

    // stage chunk CH into buffer BUF: linear LDS dest + inverse-swizzled
    // per-lane global source (rule #21; swizzle is an involution).
#define STAGE(CH, BUF) {                                                      \
        const char* sh_ = (const char*)cbh + (size_t)(ebase + (CH) * CHUNK) * 128; \
        const char* sm_ = (const char*)cbm + (size_t)(ebase + (CH) * CHUNK) * 128; \
        _Pragma("unroll")                                                     \
        for (int j = 0; j < 2; ++j) {                                         \
            int lin = (j * 256 + t) * 16;                                     \
            int src = lin ^ (((lin >> 7) & 7) << 4);                          \
            int dstb = lin - l * 16;                                          \
            GLDS16(sh_ + src, (BUF) + dstb);                                  \
            GLDS16(sm_ + src, (BUF) + 8192 + dstb);                           \
        }                                                                     \
        if (t < CHUNK) {                                                      \
            int lin = t * 16;                                                 \
            GLDS16((const char*)cnp4 + (size_t)(ebase + (CH) * CHUNK) * 16 + lin, \
                   (BUF) + 16384 + (lin - l * 16));                           \
        }                                                                     \
    }

    STAGE(0, lds);
    __syncthreads();                                 // vmcnt(0) + barrier

    for (int ch = 0; ch < NCH; ++ch) {
        char* cur = lds + (ch & 1) * BUFSZ;
        if (ch + 1 < NCH) STAGE(ch + 1, lds + ((ch + 1) & 1) * BUFSZ);

        int e0 = ebase + ch * CHUNK + lc;
#pragma unroll
        for (int tile = 0; tile < CHUNK / 16; ++tile) {
            bf16x8 bh0 = *(const bf16x8*)(cur + b0 + tile * 2048);
            bf16x8 bh1 = *(const bf16x8*)(cur + b1 + tile * 2048);
            bf16x8 bm0 = *(const bf16x8*)(cur + 8192 + b0 + tile * 2048);
            bf16x8 bm1 = *(const bf16x8*)(cur + 8192 + b1 + tile * 2048);
            f32x4  c0  = *(const f32x4*)(cur + cb0 + tile * 256);
            int eidx = e0 + tile * 16;
#pragma unroll
            for (int set = 0; set < 2; ++set) {
                f32x4 a = c0;                     // C-init = -||c||^2/2 (free)
                a = __builtin_amdgcn_mfma_f32_16x16x32_bf16(Ah[set][0].v, bh0, a, 0, 0, 0);
                a = __builtin_amdgcn_mfma_f32_16x16x32_bf16(Am[set][0].v, bh0, a, 0, 0, 0);
                a = __builtin_amdgcn_mfma_f32_16x16x32_bf16(Ah[set][0].v, bm0, a, 0, 0, 0);
                a = __builtin_amdgcn_mfma_f32_16x16x32_bf16(Ah[set][1].v, bh1, a, 0, 0, 0);
                a = __builtin_amdgcn_mfma_f32_16x16x32_bf16(Am[set][1].v, bh1, a, 0, 0, 0);
                a = __builtin_amdgcn_mfma_f32_16x16x32_bf16(Ah[set][1].v, bm1, a, 0, 0, 0);
#pragma unroll
                for (int r = 0; r < 4; ++r) {     // D: col=lc, row=lg*4+r (m89)
                    float v = a[r];               // = z.c - ||c||^2/2 exactly
                    m2[set][r] = __builtin_amdgcn_fmed3f(v, m1[set][r], m2[set][r]);
                    if (v > m1[set][r]) { m1[set][r] = v; ix[set][r] = eidx; }
                }
            }
        }
        __syncthreads();   // one barrier/chunk (r14 hazard analysis holds)
    }

    // reduce (max1,idx,max2) across the 16 column-lanes, lowest-idx tiebreak
#pragma unroll
    for (int set = 0; set < 2; ++set)
#pragma unroll
        for (int r = 0; r < 4; ++r) {
            float v1 = m1[set][r], v2 = m2[set][r]; int i1 = ix[set][r];
#pragma unroll
            for (int st = 1; st < 16; st <<= 1) {
                float o1 = __shfl_xor(v1, st, 16);
                float o2 = __shfl_xor(v2, st, 16);
                int   oi = __shfl_xor(i1, st, 16);
                float mn = fminf(v1, o1);
                v2 = fmaxf(fmaxf(v2, o2), mn);
                if (o1 > v1 || (o1 == v1 && oi < i1)) { v1 = o1; i1 = oi; }
            }
            if (lc == 0) {
                int vox = vb * 128 + w * 32 + set * 16 + lg * 4 + r;
                res[(size_t)qh * NVOX + vox] =
                    make_float4(v1, v2, __int_as_float(i1), 0.f);
            }
        }
}

// ---- path B (small ws): combine then gather, res in d_out ----
__global__ void combine_kernel(const float4* __restrict__ res, float* __restrict__ out) {
    int vox = blockIdx.x * blockDim.x + threadIdx.x;
    float v1 = -INFINITY, v2 = -INFINITY; int idx = 0;
#pragma unroll
    for (int h = 0; h < NSPLIT; ++h) {
        float4 t4 = res[(size_t)h * NVOX + vox];
        float a1 = t4.x, a2 = t4.y; int ai = __float_as_int(t4.z);
        float mn = fminf(v1, a1);
        v2 = fmaxf(fmaxf(v2, a2), mn);
        if (a1 > v1) { v1 = a1; idx = ai; }   // strict >: earlier split wins ties
    }
    unsigned flag = (v1 - v2 < CERT_EPS) ? 0x80000000u : 0u;
    ((unsigned*)out)[OFF_IDX + vox] = (unsigned)idx | flag;
}

// gather: 4 threads/row (4 independent float4 gathers each; grid 512 blocks)
// — best point of the r14/r16/r17/r18 ILP-vs-TLP sweep.
__global__ void gather_kernel(const float* __restrict__ z, const int* __restrict__ zc,
        const float* __restrict__ cb, float* __restrict__ out,
        unsigned* __restrict__ counts, float* __restrict__ sqsum,
        unsigned* __restrict__ list, unsigned* __restrict__ lcount) {
    int gid = blockIdx.x * TPB + threadIdx.x;
    int vox = gid >> 2, q = gid & 3;
    unsigned pk = ((const unsigned*)out)[OFF_IDX + vox];
    float s = 0.f;
    if (pk & 0x80000000u) {
        if (q == 0) { unsigned pos = atomicAdd(lcount, 1u); list[pos] = vox; }
    } else {
        unsigned idx = pk;
        const float4* crow = (const float4*)(cb + (size_t)idx * DIM) + q * 4;
        const float4* zrow = (const float4*)(z + (size_t)vox * DIM) + q * 4;
        float4* qrow = (float4*)(out + OFF_Q + (size_t)vox * DIM) + q * 4;
#pragma unroll
        for (int i = 0; i < 4; ++i) {
            float4 c4 = crow[i];
            float4 z4 = zrow[i];
            float dx = z4.x - c4.x, dy = z4.y - c4.y;
            float dz = z4.z - c4.z, dw = z4.w - c4.w;
            s += dx * dx + dy * dy + dz * dz + dw * dw;
            qrow[i] = c4;
        }
        if (q == 0) {
            out[OFF_IDX + vox] = (float)idx;
            atomicAdd(&counts[zc[vox * 4] * NUM_EMB + idx], 1u);
        }
    }
#pragma unroll
    for (int o = 32; o > 0; o >>= 1) s += __shfl_down(s, o, 64);
    __shared__ float red[TPB / 64];
    if ((threadIdx.x & 63) == 0) red[threadIdx.x >> 6] = s;
    __syncthreads();
    if (threadIdx.x == 0)
        atomicAdd(sqsum, red[0] + red[1] + red[2] + red[3]);
}

// ---- path A (big ws): fused combine+gather, 4 threads/row, res in ws ----
__global__ void gatherF_kernel(const float* __restrict__ z, const int* __restrict__ zc,
        const float* __restrict__ cb, const float4* __restrict__ res,
        float* __restrict__ out, unsigned* __restrict__ counts,
        float* __restrict__ sqsum, unsigned* __restrict__ list,
        unsigned* __restrict__ lcount) {
    int gid = blockIdx.x * TPB + threadIdx.x;
    int vox = gid >> 2, q = gid & 3;
    float v1 = -INFINITY, v2 = -INFINITY; int idx = 0;
#pragma unroll
    for (int h = 0; h < NSPLIT; ++h) {             // redundant in all quarters
        float4 t4 = res[(size_t)h * NVOX + vox];
        float a1 = t4.x, a2 = t4.y; int ai = __float_as_int(t4.z);
        float mn = fminf(v1, a1);
        v2 = fmaxf(fmaxf(v2, a2), mn);
        if (a1 > v1) { v1 = a1; idx = ai; }
    }
    float s = 0.f;
    if (v1 - v2 < CERT_EPS) {
        if (q == 0) { unsigned pos = atomicAdd(lcount, 1u); list[pos] = vox; }
    } else {
        const float4* crow = (const float4*)(cb + (size_t)idx * DIM) + q * 4;
        const float4* zrow = (const float4*)(z + (size_t)vox * DIM) + q * 4;
        float4* qrow = (float4*)(out + OFF_Q + (size_t)vox * DIM) + q * 4;
#pragma unroll
        for (int i = 0; i < 4; ++i) {
            float4 c4 = crow[i];
            float4 z4 = zrow[i];
            float dx = z4.x - c4.x, dy = z4.y - c4.y;
            float dz = z4.z - c4.z, dw = z4.w - c4.w;
            s += dx * dx + dy * dy + dz * dz + dw * dw;
            qrow[i] = c4;
        }
        if (q == 0) {
            out[OFF_IDX + vox] = (float)idx;
            atomicAdd(&counts[zc[vox * 4] * NUM_EMB + idx], 1u);
        }
    }
#pragma unroll
    for (int o = 32; o > 0; o >>= 1) s += __shfl_down(s, o, 64);
    __shared__ float red[TPB / 64];
    if ((threadIdx.x & 63) == 0) red[threadIdx.x >> 6] = s;
    __syncthreads();
    if (threadIdx.x == 0)
        atomicAdd(sqsum, red[0] + red[1] + red[2] + red[3]);
}

// Repair scan: r19 grid 2048 blocks (8192 waves; ~0.8 items/wave — latency-
// bound, TLP lever). Coalesced 4-entry groups, x4 interleaved reduce chains;
// exact f32 dists merged via packed (sortable<<32)|idx u64 atomicMin.
__global__ void repair_scan_kernel(const float* __restrict__ z,
        const float* __restrict__ cb, const unsigned* __restrict__ list,
        const unsigned* __restrict__ lcount,
        unsigned long long* __restrict__ merge) {
    int wid = (blockIdx.x * blockDim.x + threadIdx.x) >> 6;
    int l   = threadIdx.x & 63;
    int nw  = (gridDim.x * blockDim.x) >> 6;
    int nitems = (int)*lcount * (NUM_EMB / RCH);
    int sub = l & 15, ent = l >> 4;

    for (int it = wid; it < nitems; it += nw) {
        int k    = it / (NUM_EMB / RCH);
        int base = (it % (NUM_EMB / RCH)) * RCH;
        int vox  = list[k];
        float4 z4 = ((const float4*)(z + (size_t)vox * DIM))[sub];
        float m = INFINITY; int mi = 0;

        for (int g0 = 0; g0 < RCH / 4; g0 += 4) {
            float d[4];
#pragma unroll
            for (int u = 0; u < 4; ++u) {
                int e = base + (g0 + u) * 4 + ent;
                float4 c4 = ((const float4*)(cb + (size_t)e * DIM))[sub];
                float dx = z4.x - c4.x, dy = z4.y - c4.y;
                float dz = z4.z - c4.z, dw = z4.w - c4.w;
                d[u] = fmaf(dx, dx, fmaf(dy, dy, fmaf(dz, dz, dw * dw)));
            }
#pragma unroll
            for (int st = 1; st < 16; st <<= 1)     // 4 independent chains
#pragma unroll
                for (int u = 0; u < 4; ++u) d[u] += __shfl_xor(d[u], st, 16);
#pragma unroll
            for (int u = 0; u < 4; ++u) {
                int e = base + (g0 + u) * 4 + ent;
                if (d[u] < m) { m = d[u]; mi = e; }  // ascending e: lowest-idx
            }
        }
#pragma unroll
        for (int st = 32; st > 0; st >>= 1) {
            float om = __shfl_xor(m, st, 64);
            int   oi = __shfl_xor(mi, st, 64);
            if (om < m || (om == m && oi < mi)) { m = om; mi = oi; }
        }
        if (l == 0) {
            unsigned long long key =
                ((unsigned long long)fmap(m) << 32) | (unsigned)mi;
            atomicMin(&merge[vox], key);
        }
    }
}

// apply repaired argmin: Q row, idx, counts, sqsum for flagged rows
__global__ void repair_apply_kernel(const float* __restrict__ z,
        const int* __restrict__ zc, const float* __restrict__ cb,
        const unsigned* __restrict__ list, const unsigned* __restrict__ lcount,
        const unsigned long long* __restrict__ merge, float* __restrict__ out,
        unsigned* __restrict__ counts, float* __restrict__ sqsum) {
    int wid = (blockIdx.x * blockDim.x + threadIdx.x) >> 6;
    int l   = threadIdx.x & 63;
    int n   = (int)*lcount;
    int nw  = (gridDim.x * blockDim.x) >> 6;
    for (int k = wid; k < n; k += nw) {
        int vox = list[k];
        int mi  = (int)(merge[vox] & 0xFFFFFFFFull);
        float cv = cb[(size_t)mi * DIM + l];
        float zv = z[(size_t)vox * DIM + l];
        out[OFF_Q + (size_t)vox * DIM + l] = cv;
        float df = zv - cv;
        float s = df * df;
#pragma unroll
        for (int st = 32; st > 0; st >>= 1) s += __shfl_xor(s, st, 64);
        if (l == 0) {
            out[OFF_IDX + vox] = (float)mi;
            atomicAdd(&counts[zc[vox * 4] * NUM_EMB + mi], 1u);
            atomicAdd(sqsum, s);
        }
    }
}

// per-batch entropy/unique + fused finalize; 1024 threads/block
__global__ __launch_bounds__(STPB) void stats_final_kernel(
        const unsigned* __restrict__ counts,
        const float* __restrict__ sqsum,
        float* __restrict__ out) {
    int b = blockIdx.x;
    const unsigned* c = counts + b * NUM_EMB;

    __shared__ float sred[STPB / 64];
    float nf = 0.f;
    for (int i = threadIdx.x; i < NUM_EMB; i += STPB) nf += (float)c[i];
#pragma unroll
    for (int o = 32; o > 0; o >>= 1) nf += __shfl_down(nf, o, 64);
    if ((threadIdx.x & 63) == 0) sred[threadIdx.x >> 6] = nf;
    __syncthreads();
    float n = 0.f;
#pragma unroll
    for (int i = 0; i < STPB / 64; ++i) n += sred[i];
    __syncthreads();

    float ent = 0.f, uniq = 0.f;
    for (int i = threadIdx.x; i < NUM_EMB; i += STPB) {
        unsigned ci = c[i];
        if (ci) {
            float p = (float)ci / n;
            ent -= p * logf(p + 1e-10f);
            uniq += 1.f;
        }
    }
#pragma unroll
    for (int o = 32; o > 0; o >>= 1) {
        ent  += __shfl_down(ent, o, 64);
        uniq += __shfl_down(uniq, o, 64);
    }
    __shared__ float e4[STPB / 64], u4[STPB / 64];
    if ((threadIdx.x & 63) == 0) { e4[threadIdx.x >> 6] = ent; u4[threadIdx.x >> 6] = uniq; }
    __syncthreads();
    if (threadIdx.x == 0) {
        float eb = 0.f, ub = 0.f;
#pragma unroll
        for (int i = 0; i < STPB / 64; ++i) { eb += e4[i]; ub += u4[i]; }
        atomicAdd(&out[OFF_ENT],  eb * 0.25f);
        atomicAdd(&out[OFF_PERP], expf(eb) * 0.25f);
        atomicAdd(&out[OFF_UNIQ], ub * 0.25f);
        atomicAdd(&out[OFF_UTIL], ub * (100.f / (4.f * NUM_EMB)));
        if (b == 0) {
            float loss = *sqsum / (float)((size_t)NVOX * DIM);
            out[OFF_VQ]   = loss;
            out[OFF_COMM] = loss;
        }
    }
}

extern "C" void kernel_launch(void* const* d_in, const int* in_sizes, int n_in,
                              void* d_out, int out_size, void* d_ws, size_t ws_size,
                              hipStream_t stream) {
    const float* z  = (const float*)d_in[0];
    const int*   zc = (const int*)d_in[1];
    const float* cb = (const float*)d_in[2];
    float* out = (float*)d_out;
    char* ws = (char*)d_ws;

    // d_out scratch: cbh 1MB | cbm 1MB at Q floats [0, 524288).
    unsigned short* cbh = (unsigned short*)out;
    unsigned short* cbm = cbh + NUM_EMB * DIM;

    unsigned* counts = (unsigned*)ws;                       // 131072 B
    unsigned* list   = (unsigned*)(ws + 131072);            // 131072 B
    unsigned* misc   = (unsigned*)(ws + 262144);            // 64 B
    unsigned* lcount = misc;
    float*    sqsum  = (float*)(ws + 262148);
    float*    cnp4   = (float*)(ws + 262208);               // 131072 B
    unsigned long long* merge = (unsigned long long*)(ws + 393280); // 262144 B
    // path A: res in ws (2MB) -> fused combine+gather
    size_t res_ws_off = 655424;
    bool bigws = ws_size >= res_ws_off + (size_t)NSPLIT * NVOX * 16;
    float4* res = bigws ? (float4*)(ws + res_ws_off)
                        : (float4*)(out + 524288);  // path B: floats [524288,1048576)

    prep_kernel<<<NUM_EMB / 4, TPB, 0, stream>>>(cb, cbh, cbm, cnp4, counts,
                                                 misc, merge, out);
    argmin_kernel<<<(NVOX / 128) * NSPLIT, TPB, 0, stream>>>(z, cbh, cbm, cnp4, res);
    if (bigws) {
        gatherF_kernel<<<(NVOX * 4) / TPB, TPB, 0, stream>>>(z, zc, cb, res, out,
                                                             counts, sqsum, list, lcount);
    } else {
        combine_kernel<<<NVOX / TPB, TPB, 0, stream>>>(res, out);
        gather_kernel<<<(NVOX * 4) / TPB, TPB, 0, stream>>>(z, zc, cb, out, counts,
                                                            sqsum, list, lcount);
    }
    repair_scan_kernel<<<2048, TPB, 0, stream>>>(z, cb, list, lcount, merge);
    repair_apply_kernel<<<256, TPB, 0, stream>>>(z, zc, cb, list, lcount, merge,
                                                 out, counts, sqsum);
    stats_final_kernel<<<NBATCH, STPB, 0, stream>>>(counts, sqsum, out);
}